// Round 5
// baseline (926.124 us; speedup 1.0000x reference)
//
#include <hip/hip_runtime.h>
#include <hip/hip_bf16.h>

typedef unsigned short u16;
typedef __attribute__((ext_vector_type(8))) short short8;
typedef __attribute__((ext_vector_type(4))) float f32x4;
typedef __attribute__((ext_vector_type(8))) unsigned short ushort8v;

#define NVOX 200000
#define NVP  200064
#define NOFF 27
#define NBLK 1563

__device__ __forceinline__ u16 f2bf(float f) {
    __hip_bfloat16 h = __float2bfloat16(f);
    return *reinterpret_cast<u16*>(&h);
}
__device__ __forceinline__ float bf2f(u16 u) {
    union { unsigned int i; float f; } v;
    v.i = ((unsigned int)u) << 16;
    return v.f;
}

#define GLOAD_LDS16(g, l)                                                     \
    __builtin_amdgcn_global_load_lds(                                         \
        (const __attribute__((address_space(1))) unsigned int*)(g),           \
        (__attribute__((address_space(3))) unsigned int*)(l), 16, 0, 0)

// ---------------------------------------------------------------------------
// prep: cast x -> bf16; repack W1/W2 fragment-major; zero page.
// ---------------------------------------------------------------------------
__global__ __launch_bounds__(256) void prep_kernel(
    const float* __restrict__ x, const float* __restrict__ W1,
    const float* __restrict__ W2, u16* __restrict__ xb,
    u16* __restrict__ w1t, u16* __restrict__ w2t, float* __restrict__ zbuf)
{
    const int XV = NVOX * 96 / 4;     // 4,800,000 vec4 cast jobs
    const int WC = 62208;             // W chunk jobs per conv (27*36*64)
    int t = blockIdx.x * 256 + threadIdx.x;
    if (blockIdx.x == 0 && threadIdx.x < 64) zbuf[threadIdx.x] = 0.f;
    if (t < XV) {
        float4 v = *(const float4*)(x + (size_t)t * 4);
        ushort4 o;
        o.x = f2bf(v.x); o.y = f2bf(v.y); o.z = f2bf(v.z); o.w = f2bf(v.w);
        *(ushort4*)(xb + (size_t)t * 4) = o;
    } else if (t < XV + WC) {
        int j = t - XV;
        int lane = j & 63, rest = j >> 6;
        int nco = rest % 12, rest2 = rest / 12;
        int ks = rest2 % 3, off = rest2 / 3;
        int co = nco * 16 + (lane & 15);
        int kb = ks * 32 + (lane >> 4) * 8;
        const float* src = W1 + (size_t)off * 18432 + (size_t)kb * 192 + co;
        ushort8v ov;
#pragma unroll
        for (int jj = 0; jj < 8; ++jj) ov[jj] = f2bf(src[(size_t)jj * 192]);
        *(ushort8v*)(w1t + (size_t)j * 8) = ov;
    } else if (t < XV + 2 * WC) {
        int j = t - XV - WC;
        int lane = j & 63, rest = j >> 6;
        int nco = rest % 6, rest2 = rest / 6;
        int kk = rest2 % 6, off = rest2 / 6;
        int co = nco * 16 + (lane & 15);
        int kb = kk * 32 + (lane >> 4) * 8;
        const float* src = W2 + (size_t)off * 18432 + (size_t)kb * 96 + co;
        ushort8v ov;
#pragma unroll
        for (int jj = 0; jj < 8; ++jj) ov[jj] = f2bf(src[(size_t)jj * 96]);
        *(ushort8v*)(w2t + (size_t)j * 8) = ov;
    }
}

// ---------------------------------------------------------------------------
// lsrc precompute: lsrcG[off][row] = mask>0 ? idx : -1  (rows padded to NVP)
// ---------------------------------------------------------------------------
__global__ __launch_bounds__(256) void lsrc_kernel(
    const int* __restrict__ idxp, const int* __restrict__ mskp,
    int* __restrict__ lsrcG)
{
    int r = blockIdx.x * 256 + threadIdx.x;
    int o = blockIdx.y;
    if (r < NVP) {
        int v = -1;
        if (r < NVOX) {
            if (mskp[(size_t)o * NVOX + r] > 0) v = idxp[(size_t)o * NVOX + r];
        }
        lsrcG[(size_t)o * NVP + r] = v;
    }
}

// ---------------------------------------------------------------------------
// conv: explicit-GEMM sparse conv, bf16 MFMA, f32 accum.
//   A: global_load_lds double-buffer, chunk-major LDS [12][128] (conflict-free
//      b128 reads), masked rows from a zero page, lsrc precomputed in global.
//   W: per-wave register frags from fragment-major layout (L2-hot).
//   1 barrier/step. Epilogue: fused BN partial sums + bf16 store.
// ---------------------------------------------------------------------------
template<int COUT, int WN, int HFDIV>
__global__ __launch_bounds__(512, 6) void conv_mfma(
    const u16* __restrict__ xb, const int* __restrict__ lsrcG,
    const u16* __restrict__ Wt, const float* __restrict__ zbuf,
    u16* __restrict__ hout, float* __restrict__ part)
{
    constexpr int CIN  = 96 * HFDIV;
    constexpr int WM   = 8 / WN;
    constexpr int FM   = 128 / (WM * 16);
    constexpr int FN   = COUT / (WN * 16);
    constexpr int NCO  = COUT / 16;
    constexpr int SG   = NOFF * HFDIV;     // K-steps total
    constexpr int BUFU = 12 * 128 * 8;     // u16 per A buffer (24 KB)

    __shared__ u16 ldsA[2 * BUFU];         // 49152 B

    const int tid  = threadIdx.x;
    const int row0 = blockIdx.x * 128;
    const int lane = tid & 63;
    const int wid  = tid >> 6;
    const int wm   = wid / WN;
    const int wn   = wid % WN;
    const int lr   = lane & 15;
    const int lk   = lane >> 4;

    // staging: thread stages row (tid&127), chunks c0, c0+4, c0+8
    const int rStage = tid & 127;
    const int c0 = tid >> 7;
    const int ldsWaveBase = (tid & ~63) * 8;   // u16, HW adds lane*16B

    // A-read: af[m] at u16 offset (ks*4+lk)*1024 + r*8
    int rdBase[FM];
#pragma unroll
    for (int m = 0; m < FM; ++m) {
        int r = wm * (FM * 16) + m * 16 + lr;
        rdBase[m] = r * 8 + lk * 1024;
    }
    const u16* wtw = Wt + (size_t)(wn * FN) * 512 + (size_t)lane * 8;

    f32x4 acc[FM][FN];
#pragma unroll
    for (int m = 0; m < FM; ++m)
#pragma unroll
        for (int n = 0; n < FN; ++n)
            acc[m][n] = (f32x4){0.f, 0.f, 0.f, 0.f};

    auto issueA = [&](int s, int bufSel) {
        int offIdx = (HFDIV == 1) ? s : (s >> 1);
        int hf     = (HFDIV == 1) ? 0 : (s & 1);
        int sv = lsrcG[(size_t)offIdx * NVP + row0 + rStage];
        const u16* g = (sv >= 0)
            ? (xb + (size_t)sv * CIN + hf * 96 + c0 * 8)
            : ((const u16*)zbuf + c0 * 8);
#pragma unroll
        for (int it = 0; it < 3; ++it)
            GLOAD_LDS16(g + it * 32,
                        ldsA + bufSel * BUFU + it * 4096 + ldsWaveBase);
    };

    issueA(0, 0);
    __syncthreads();   // implicit vmcnt(0): A(0) resident

    int bufSel = 0;
#pragma unroll 1
    for (int s = 0; s < SG; ++s) {
        if (s + 1 < SG) issueA(s + 1, bufSel ^ 1);
        const u16* abuf = ldsA + bufSel * BUFU;
#pragma unroll
        for (int ks = 0; ks < 3; ++ks) {
            int kidx = 3 * s + ks;
            short8 bf_[FN];
#pragma unroll
            for (int n = 0; n < FN; ++n)
                bf_[n] = *(const short8*)(wtw + ((size_t)kidx * NCO + n) * 512);
#pragma unroll
            for (int m = 0; m < FM; ++m) {
                short8 af = *(const short8*)(abuf + rdBase[m] + ks * 4096);
#pragma unroll
                for (int n = 0; n < FN; ++n)
                    acc[m][n] = __builtin_amdgcn_mfma_f32_16x16x32_bf16(
                        af, bf_[n], acc[m][n], 0, 0, 0);
            }
        }
        __syncthreads();
        bufSel ^= 1;
    }

    // ---- fused BN statsA: per-block partial sum/sumsq per channel ----
    float* smf = (float*)ldsA;             // overlay [WM][COUT][2]
#pragma unroll
    for (int n = 0; n < FN; ++n) {
        float s1 = 0.f, s2 = 0.f;
#pragma unroll
        for (int m = 0; m < FM; ++m)
#pragma unroll
            for (int q = 0; q < 4; ++q) {
                float v = acc[m][n][q];
                s1 += v; s2 += v * v;
            }
        s1 += __shfl_xor(s1, 16); s1 += __shfl_xor(s1, 32);
        s2 += __shfl_xor(s2, 16); s2 += __shfl_xor(s2, 32);
        if (lane < 16) {
            int col = wn * (FN * 16) + n * 16 + lr;
            smf[(wm * COUT + col) * 2 + 0] = s1;
            smf[(wm * COUT + col) * 2 + 1] = s2;
        }
    }
    __syncthreads();
    if (tid < 2 * COUT) {
        int z = tid / COUT, cc = tid % COUT;
        float v = 0.f;
#pragma unroll
        for (int w = 0; w < WM; ++w) v += smf[(w * COUT + cc) * 2 + z];
        part[(size_t)blockIdx.x * (2 * COUT) + z * COUT + cc] = v;
    }

    // ---- store h (bf16): D layout col=lane&15, row=(lane>>4)*4+q ----
#pragma unroll
    for (int m = 0; m < FM; ++m) {
#pragma unroll
        for (int q = 0; q < 4; ++q) {
            int row = row0 + wm * (FM * 16) + m * 16 + lk * 4 + q;
            if (row < NVOX) {
#pragma unroll
                for (int n = 0; n < FN; ++n) {
                    int col = wn * (FN * 16) + n * 16 + lr;
                    hout[(size_t)row * COUT + col] = f2bf(acc[m][n][q]);
                }
            }
        }
    }
}

// ---------------------------------------------------------------------------
// BN stats reduce: sum partials over NBLK blocks, emit scale/shift
// ---------------------------------------------------------------------------
template<int COUT>
__global__ __launch_bounds__(256) void bn_statsB(
    const float* __restrict__ part, const float* __restrict__ g,
    const float* __restrict__ bv, float* __restrict__ ss)
{
    const int c = blockIdx.x;
    const int t = threadIdx.x;
    float s1 = 0.f, s2 = 0.f;
    for (int b = t; b < NBLK; b += 256) {
        s1 += part[(size_t)b * 2 * COUT + c];
        s2 += part[(size_t)b * 2 * COUT + COUT + c];
    }
#pragma unroll
    for (int d = 1; d < 64; d <<= 1) {
        s1 += __shfl_xor(s1, d);
        s2 += __shfl_xor(s2, d);
    }
    __shared__ float rs[8];
    int w = t >> 6;
    if ((t & 63) == 0) { rs[w] = s1; rs[4 + w] = s2; }
    __syncthreads();
    if (t == 0) {
        s1 = rs[0] + rs[1] + rs[2] + rs[3];
        s2 = rs[4] + rs[5] + rs[6] + rs[7];
        float mu  = s1 * (1.0f / NVOX);
        float var = s2 * (1.0f / NVOX) - mu * mu;
        float sc  = g[c] * rsqrtf(var + 1e-5f);
        ss[c] = sc;
        ss[COUT + c] = bv[c] - mu * sc;
    }
}

// ---------------------------------------------------------------------------
// apply BN + ReLU in place (bf16), vec8
// ---------------------------------------------------------------------------
template<int COUT>
__global__ __launch_bounds__(256) void bn_apply_relu(
    u16* __restrict__ h, const float* __restrict__ ss)
{
    int t = blockIdx.x * 256 + threadIdx.x;   // < NVOX*COUT/8
    int c0 = (t * 8) % COUT;
    ushort8v v = *(ushort8v*)(h + (size_t)t * 8);
#pragma unroll
    for (int j = 0; j < 8; ++j) {
        float f = bf2f(v[j]);
        f = fmaxf(f * ss[c0 + j] + ss[COUT + c0 + j], 0.f);
        v[j] = f2bf(f);
    }
    *(ushort8v*)(h + (size_t)t * 8) = v;
}

// ---------------------------------------------------------------------------
// final: out = relu(scale2*h2 + shift2 + x), f32 out, vec8
// ---------------------------------------------------------------------------
__global__ __launch_bounds__(256) void final_kernel(
    const u16* __restrict__ h2, const float* __restrict__ x,
    const float* __restrict__ ss, float* __restrict__ out)
{
    int t = blockIdx.x * 256 + threadIdx.x;   // < NVOX*96/8
    int c0 = (t * 8) % 96;
    ushort8v v = *(const ushort8v*)(h2 + (size_t)t * 8);
    float4 x0 = *(const float4*)(x + (size_t)t * 8);
    float4 x1 = *(const float4*)(x + (size_t)t * 8 + 4);
    float xs[8] = {x0.x, x0.y, x0.z, x0.w, x1.x, x1.y, x1.z, x1.w};
    float o[8];
#pragma unroll
    for (int j = 0; j < 8; ++j) {
        float f = bf2f(v[j]) * ss[c0 + j] + ss[96 + c0 + j] + xs[j];
        o[j] = fmaxf(f, 0.f);
    }
    *(float4*)(out + (size_t)t * 8)     = (float4){o[0], o[1], o[2], o[3]};
    *(float4*)(out + (size_t)t * 8 + 4) = (float4){o[4], o[5], o[6], o[7]};
}

// ---------------------------------------------------------------------------
extern "C" void kernel_launch(void* const* d_in, const int* in_sizes, int n_in,
                              void* d_out, int out_size, void* d_ws, size_t ws_size,
                              hipStream_t stream)
{
    const float* x    = (const float*)d_in[0];
    const int*   idx  = (const int*)d_in[1];
    const int*   mask = (const int*)d_in[2];
    const float* W1   = (const float*)d_in[3];
    const float* g1   = (const float*)d_in[4];
    const float* b1   = (const float*)d_in[5];
    const float* W2   = (const float*)d_in[6];
    const float* g2   = (const float*)d_in[7];
    const float* b2   = (const float*)d_in[8];

    unsigned char* ws = (unsigned char*)d_ws;
    u16*  xb    = (u16*)ws;                          // 38,400,000 B
    u16*  w1t   = (u16*)(ws + 38400000);             //    995,328 B
    u16*  w2t   = (u16*)(ws + 39395328);             //    995,328 B
    u16*  h2    = (u16*)(ws + 40390656);             // 38,400,000 B
    float* part = (float*)(ws + 78790656);           //  2,400,768 B
    float* ss1  = (float*)(ws + 81191424);           //      1,536 B
    float* ss2  = (float*)(ws + 81192960);           //        768 B
    float* zbuf = (float*)(ws + 81193728);           //        256 B
    int*  lsrcG = (int*)(ws + 81193984);             // 21,606,912 B (27*200064*4)

    u16* h = (u16*)d_out;         // reuse d_out (76.8MB) as [N][192] bf16

    prep_kernel<<<19236, 256, 0, stream>>>(x, W1, W2, xb, w1t, w2t, zbuf);
    lsrc_kernel<<<dim3(782, 27), 256, 0, stream>>>(idx, mask, lsrcG);

    // conv1: COUT=192, 2m x 4n waves, K=96 per offset
    conv_mfma<192, 4, 1><<<NBLK, 512, 0, stream>>>(xb, lsrcG, w1t, zbuf, h, part);
    bn_statsB<192><<<192, 256, 0, stream>>>(part, g1, b1, ss1);
    bn_apply_relu<192><<<18750, 256, 0, stream>>>(h, ss1);

    // conv2: COUT=96, 4m x 2n waves, K=192 in two 96-phases per offset
    conv_mfma<96, 2, 2><<<NBLK, 512, 0, stream>>>(h, lsrcG, w2t, zbuf, h2, part);
    bn_statsB<96><<<96, 256, 0, stream>>>(part, g2, b2, ss2);
    final_kernel<<<9375, 256, 0, stream>>>(h2, x, ss2, (float*)d_out);
}

// Round 6
// 752.842 us; speedup vs baseline: 1.2302x; 1.2302x over previous
//
#include <hip/hip_runtime.h>
#include <hip/hip_bf16.h>

typedef unsigned short u16;
typedef __attribute__((ext_vector_type(8))) short short8;
typedef __attribute__((ext_vector_type(4))) float f32x4;
typedef __attribute__((ext_vector_type(8))) unsigned short ushort8v;

#define NVOX 200000
#define NVP  200064
#define NOFF 27
#define NBLK 1563

__device__ __forceinline__ u16 f2bf(float f) {
    __hip_bfloat16 h = __float2bfloat16(f);
    return *reinterpret_cast<u16*>(&h);
}
__device__ __forceinline__ float bf2f(u16 u) {
    union { unsigned int i; float f; } v;
    v.i = ((unsigned int)u) << 16;
    return v.f;
}

#define GLOAD_LDS16(g, l)                                                     \
    __builtin_amdgcn_global_load_lds(                                         \
        (const __attribute__((address_space(1))) unsigned int*)(g),           \
        (__attribute__((address_space(3))) unsigned int*)(l), 16, 0, 0)

// ---------------------------------------------------------------------------
// prep: cast x -> bf16; repack W1/W2 fragment-major; zero page.
// ---------------------------------------------------------------------------
__global__ __launch_bounds__(256) void prep_kernel(
    const float* __restrict__ x, const float* __restrict__ W1,
    const float* __restrict__ W2, u16* __restrict__ xb,
    u16* __restrict__ w1t, u16* __restrict__ w2t, float* __restrict__ zbuf)
{
    const int XV = NVOX * 96 / 4;     // 4,800,000 vec4 cast jobs
    const int WC = 62208;             // W chunk jobs per conv (27*36*64)
    int t = blockIdx.x * 256 + threadIdx.x;
    if (blockIdx.x == 0 && threadIdx.x < 64) zbuf[threadIdx.x] = 0.f;
    if (t < XV) {
        float4 v = *(const float4*)(x + (size_t)t * 4);
        ushort4 o;
        o.x = f2bf(v.x); o.y = f2bf(v.y); o.z = f2bf(v.z); o.w = f2bf(v.w);
        *(ushort4*)(xb + (size_t)t * 4) = o;
    } else if (t < XV + WC) {
        int j = t - XV;
        int lane = j & 63, rest = j >> 6;
        int nco = rest % 12, rest2 = rest / 12;
        int ks = rest2 % 3, off = rest2 / 3;
        int co = nco * 16 + (lane & 15);
        int kb = ks * 32 + (lane >> 4) * 8;
        const float* src = W1 + (size_t)off * 18432 + (size_t)kb * 192 + co;
        ushort8v ov;
#pragma unroll
        for (int jj = 0; jj < 8; ++jj) ov[jj] = f2bf(src[(size_t)jj * 192]);
        *(ushort8v*)(w1t + (size_t)j * 8) = ov;
    } else if (t < XV + 2 * WC) {
        int j = t - XV - WC;
        int lane = j & 63, rest = j >> 6;
        int nco = rest % 6, rest2 = rest / 6;
        int kk = rest2 % 6, off = rest2 / 6;
        int co = nco * 16 + (lane & 15);
        int kb = kk * 32 + (lane >> 4) * 8;
        const float* src = W2 + (size_t)off * 18432 + (size_t)kb * 96 + co;
        ushort8v ov;
#pragma unroll
        for (int jj = 0; jj < 8; ++jj) ov[jj] = f2bf(src[(size_t)jj * 96]);
        *(ushort8v*)(w2t + (size_t)j * 8) = ov;
    }
}

// ---------------------------------------------------------------------------
// lsrc precompute: lsrcG[off][row] = mask>0 ? idx : -1  (rows padded to NVP)
// ---------------------------------------------------------------------------
__global__ __launch_bounds__(256) void lsrc_kernel(
    const int* __restrict__ idxp, const int* __restrict__ mskp,
    int* __restrict__ lsrcG)
{
    int r = blockIdx.x * 256 + threadIdx.x;
    int o = blockIdx.y;
    if (r < NVP) {
        int v = -1;
        if (r < NVOX) {
            if (mskp[(size_t)o * NVOX + r] > 0) v = idxp[(size_t)o * NVOX + r];
        }
        lsrcG[(size_t)o * NVP + r] = v;
    }
}

// ---------------------------------------------------------------------------
// conv: explicit-GEMM sparse conv, bf16 MFMA, f32 accum.
//   A: global_load_lds double-buffer, chunk-major LDS [12][128] (conflict-free
//      b128 reads), masked rows from a zero page, lsrc precomputed in global.
//   W: whole-step register frags loaded BEFORE the A-gather issue so the
//      compiler can wait on them with a counted vmcnt(3) while the gather
//      stays in flight (vmcnt is FIFO).  1 barrier/step, no mid-step drains.
//   Epilogue: fused BN partial sums + bf16 store.
// ---------------------------------------------------------------------------
template<int COUT, int WN, int HFDIV, int MINW>
__global__ __launch_bounds__(512, MINW) void conv_mfma(
    const u16* __restrict__ xb, const int* __restrict__ lsrcG,
    const u16* __restrict__ Wt, const float* __restrict__ zbuf,
    u16* __restrict__ hout, float* __restrict__ part)
{
    constexpr int CIN  = 96 * HFDIV;
    constexpr int WM   = 8 / WN;
    constexpr int FM   = 128 / (WM * 16);
    constexpr int FN   = COUT / (WN * 16);
    constexpr int NCO  = COUT / 16;
    constexpr int SG   = NOFF * HFDIV;     // K-steps total
    constexpr int BUFU = 12 * 128 * 8;     // u16 per A buffer (24 KB)

    __shared__ u16 ldsA[2 * BUFU];         // 49152 B

    const int tid  = threadIdx.x;
    const int row0 = blockIdx.x * 128;
    const int lane = tid & 63;
    const int wid  = tid >> 6;
    const int wm   = wid / WN;
    const int wn   = wid % WN;
    const int lr   = lane & 15;
    const int lk   = lane >> 4;

    // staging: thread stages row (tid&127), chunks c0, c0+4, c0+8
    const int rStage = tid & 127;
    const int c0 = tid >> 7;
    const int ldsWaveBase = (tid & ~63) * 8;   // u16, HW adds lane*16B

    // A-read: af[m] at u16 offset (ks*4+lk)*1024 + r*8
    int rdBase[FM];
#pragma unroll
    for (int m = 0; m < FM; ++m) {
        int r = wm * (FM * 16) + m * 16 + lr;
        rdBase[m] = r * 8 + lk * 1024;
    }
    const u16* wtw = Wt + (size_t)(wn * FN) * 512 + (size_t)lane * 8;

    f32x4 acc[FM][FN];
#pragma unroll
    for (int m = 0; m < FM; ++m)
#pragma unroll
        for (int n = 0; n < FN; ++n)
            acc[m][n] = (f32x4){0.f, 0.f, 0.f, 0.f};

    auto issueA = [&](int s, int bufSel) {
        int offIdx = (HFDIV == 1) ? s : (s >> 1);
        int hf     = (HFDIV == 1) ? 0 : (s & 1);
        int sv = lsrcG[(size_t)offIdx * NVP + row0 + rStage];
        const u16* g = (sv >= 0)
            ? (xb + (size_t)sv * CIN + hf * 96 + c0 * 8)
            : ((const u16*)zbuf + c0 * 8);
#pragma unroll
        for (int it = 0; it < 3; ++it)
            GLOAD_LDS16(g + it * 32,
                        ldsA + bufSel * BUFU + it * 4096 + ldsWaveBase);
    };

    issueA(0, 0);
    __syncthreads();   // implicit vmcnt(0): A(0) resident

    short8 wreg[3][FN];
    int bufSel = 0;
#pragma unroll 1
    for (int s = 0; s < SG; ++s) {
        // ---- W frags for the whole step, issued FIRST (FIFO-counted wait)
#pragma unroll
        for (int ks = 0; ks < 3; ++ks)
#pragma unroll
            for (int n = 0; n < FN; ++n)
                wreg[ks][n] = *(const short8*)(
                    wtw + ((size_t)(3 * s + ks) * NCO + n) * 512);
        __builtin_amdgcn_sched_barrier(0);
        // ---- A gather for next step, issued AFTER W (stays in flight)
        if (s + 1 < SG) issueA(s + 1, bufSel ^ 1);
        __builtin_amdgcn_sched_barrier(0);
        // ---- MFMA phase: only waits W (vmcnt(3)) and LDS (lgkm)
        const u16* abuf = ldsA + bufSel * BUFU;
#pragma unroll
        for (int ks = 0; ks < 3; ++ks) {
#pragma unroll
            for (int m = 0; m < FM; ++m) {
                short8 af = *(const short8*)(abuf + rdBase[m] + ks * 4096);
#pragma unroll
                for (int n = 0; n < FN; ++n)
                    acc[m][n] = __builtin_amdgcn_mfma_f32_16x16x32_bf16(
                        af, wreg[ks][n], acc[m][n], 0, 0, 0);
            }
        }
        __syncthreads();   // drains next-step gather; syncs dbuf swap
        bufSel ^= 1;
    }

    // ---- fused BN statsA: per-block partial sum/sumsq per channel ----
    float* smf = (float*)ldsA;             // overlay [WM][COUT][2]
#pragma unroll
    for (int n = 0; n < FN; ++n) {
        float s1 = 0.f, s2 = 0.f;
#pragma unroll
        for (int m = 0; m < FM; ++m)
#pragma unroll
            for (int q = 0; q < 4; ++q) {
                float v = acc[m][n][q];
                s1 += v; s2 += v * v;
            }
        s1 += __shfl_xor(s1, 16); s1 += __shfl_xor(s1, 32);
        s2 += __shfl_xor(s2, 16); s2 += __shfl_xor(s2, 32);
        if (lane < 16) {
            int col = wn * (FN * 16) + n * 16 + lr;
            smf[(wm * COUT + col) * 2 + 0] = s1;
            smf[(wm * COUT + col) * 2 + 1] = s2;
        }
    }
    __syncthreads();
    if (tid < 2 * COUT) {
        int z = tid / COUT, cc = tid % COUT;
        float v = 0.f;
#pragma unroll
        for (int w = 0; w < WM; ++w) v += smf[(w * COUT + cc) * 2 + z];
        part[(size_t)blockIdx.x * (2 * COUT) + z * COUT + cc] = v;
    }

    // ---- store h (bf16): D layout col=lane&15, row=(lane>>4)*4+q ----
#pragma unroll
    for (int m = 0; m < FM; ++m) {
#pragma unroll
        for (int q = 0; q < 4; ++q) {
            int row = row0 + wm * (FM * 16) + m * 16 + lk * 4 + q;
            if (row < NVOX) {
#pragma unroll
                for (int n = 0; n < FN; ++n) {
                    int col = wn * (FN * 16) + n * 16 + lr;
                    hout[(size_t)row * COUT + col] = f2bf(acc[m][n][q]);
                }
            }
        }
    }
}

// ---------------------------------------------------------------------------
// BN stats reduce: sum partials over NBLK blocks, emit scale/shift
// ---------------------------------------------------------------------------
template<int COUT>
__global__ __launch_bounds__(256) void bn_statsB(
    const float* __restrict__ part, const float* __restrict__ g,
    const float* __restrict__ bv, float* __restrict__ ss)
{
    const int c = blockIdx.x;
    const int t = threadIdx.x;
    float s1 = 0.f, s2 = 0.f;
    for (int b = t; b < NBLK; b += 256) {
        s1 += part[(size_t)b * 2 * COUT + c];
        s2 += part[(size_t)b * 2 * COUT + COUT + c];
    }
#pragma unroll
    for (int d = 1; d < 64; d <<= 1) {
        s1 += __shfl_xor(s1, d);
        s2 += __shfl_xor(s2, d);
    }
    __shared__ float rs[8];
    int w = t >> 6;
    if ((t & 63) == 0) { rs[w] = s1; rs[4 + w] = s2; }
    __syncthreads();
    if (t == 0) {
        s1 = rs[0] + rs[1] + rs[2] + rs[3];
        s2 = rs[4] + rs[5] + rs[6] + rs[7];
        float mu  = s1 * (1.0f / NVOX);
        float var = s2 * (1.0f / NVOX) - mu * mu;
        float sc  = g[c] * rsqrtf(var + 1e-5f);
        ss[c] = sc;
        ss[COUT + c] = bv[c] - mu * sc;
    }
}

// ---------------------------------------------------------------------------
// apply BN + ReLU in place (bf16), vec8
// ---------------------------------------------------------------------------
template<int COUT>
__global__ __launch_bounds__(256) void bn_apply_relu(
    u16* __restrict__ h, const float* __restrict__ ss)
{
    int t = blockIdx.x * 256 + threadIdx.x;   // < NVOX*COUT/8
    int c0 = (t * 8) % COUT;
    ushort8v v = *(ushort8v*)(h + (size_t)t * 8);
#pragma unroll
    for (int j = 0; j < 8; ++j) {
        float f = bf2f(v[j]);
        f = fmaxf(f * ss[c0 + j] + ss[COUT + c0 + j], 0.f);
        v[j] = f2bf(f);
    }
    *(ushort8v*)(h + (size_t)t * 8) = v;
}

// ---------------------------------------------------------------------------
// final: out = relu(scale2*h2 + shift2 + x), f32 out, vec8
// ---------------------------------------------------------------------------
__global__ __launch_bounds__(256) void final_kernel(
    const u16* __restrict__ h2, const float* __restrict__ x,
    const float* __restrict__ ss, float* __restrict__ out)
{
    int t = blockIdx.x * 256 + threadIdx.x;   // < NVOX*96/8
    int c0 = (t * 8) % 96;
    ushort8v v = *(const ushort8v*)(h2 + (size_t)t * 8);
    float4 x0 = *(const float4*)(x + (size_t)t * 8);
    float4 x1 = *(const float4*)(x + (size_t)t * 8 + 4);
    float xs[8] = {x0.x, x0.y, x0.z, x0.w, x1.x, x1.y, x1.z, x1.w};
    float o[8];
#pragma unroll
    for (int j = 0; j < 8; ++j) {
        float f = bf2f(v[j]) * ss[c0 + j] + ss[96 + c0 + j] + xs[j];
        o[j] = fmaxf(f, 0.f);
    }
    *(float4*)(out + (size_t)t * 8)     = (float4){o[0], o[1], o[2], o[3]};
    *(float4*)(out + (size_t)t * 8 + 4) = (float4){o[4], o[5], o[6], o[7]};
}

// ---------------------------------------------------------------------------
extern "C" void kernel_launch(void* const* d_in, const int* in_sizes, int n_in,
                              void* d_out, int out_size, void* d_ws, size_t ws_size,
                              hipStream_t stream)
{
    const float* x    = (const float*)d_in[0];
    const int*   idx  = (const int*)d_in[1];
    const int*   mask = (const int*)d_in[2];
    const float* W1   = (const float*)d_in[3];
    const float* g1   = (const float*)d_in[4];
    const float* b1   = (const float*)d_in[5];
    const float* W2   = (const float*)d_in[6];
    const float* g2   = (const float*)d_in[7];
    const float* b2   = (const float*)d_in[8];

    unsigned char* ws = (unsigned char*)d_ws;
    u16*  xb    = (u16*)ws;                          // 38,400,000 B
    u16*  w1t   = (u16*)(ws + 38400000);             //    995,328 B
    u16*  w2t   = (u16*)(ws + 39395328);             //    995,328 B
    u16*  h2    = (u16*)(ws + 40390656);             // 38,400,000 B
    float* part = (float*)(ws + 78790656);           //  2,400,768 B
    float* ss1  = (float*)(ws + 81191424);           //      1,536 B
    float* ss2  = (float*)(ws + 81192960);           //        768 B
    float* zbuf = (float*)(ws + 81193728);           //        256 B
    int*  lsrcG = (int*)(ws + 81193984);             // 21,606,912 B (27*200064*4)

    u16* h = (u16*)d_out;         // reuse d_out (76.8MB) as [N][192] bf16

    prep_kernel<<<19236, 256, 0, stream>>>(x, W1, W2, xb, w1t, w2t, zbuf);
    lsrc_kernel<<<dim3(782, 27), 256, 0, stream>>>(idx, mask, lsrcG);

    // conv1: COUT=192, 2m x 4n waves, K=96 per offset, 2 blocks/CU (VGPR)
    conv_mfma<192, 4, 1, 4><<<NBLK, 512, 0, stream>>>(xb, lsrcG, w1t, zbuf, h, part);
    bn_statsB<192><<<192, 256, 0, stream>>>(part, g1, b1, ss1);
    bn_apply_relu<192><<<18750, 256, 0, stream>>>(h, ss1);

    // conv2: COUT=96, 4m x 2n waves, K=192 in two 96-phases, 3 blocks/CU
    conv_mfma<96, 2, 2, 6><<<NBLK, 512, 0, stream>>>(h, lsrcG, w2t, zbuf, h2, part);
    bn_statsB<96><<<96, 256, 0, stream>>>(part, g2, b2, ss2);
    final_kernel<<<9375, 256, 0, stream>>>(h2, x, ss2, (float*)d_out);
}